// Round 14
// baseline (136.023 us; speedup 1.0000x reference)
//
#include <hip/hip_runtime.h>

#define N_NODES 50000
#define N_EDGES 800000
#define D 64
#define H 128
#define NLIVE 98       // live 512-node buckets = ceil(50000/512)
#define NBPAD 128      // padded bin arrays for scans
#define BT 2048        // edges per level-1 tile
#define NBB 391        // ceil(N_EDGES/BT)
#define CAPT 52        // slots per (tile,bucket) segment (mean 21, sigma 4.6)
#define STG 1408       // stage cap per (bucket,eighth) (mean 1024, sigma 32, +12s)
#define CVB 798        // conversion blocks: ceil((800000+16384)/1024)

typedef __attribute__((ext_vector_type(8))) short  short8;   // 8 bf16
typedef __attribute__((ext_vector_type(4))) float  floatx4;
typedef __attribute__((ext_vector_type(4))) unsigned short ushort4v;

__device__ inline unsigned short f2bf(float f) {   // round-to-nearest-even
    unsigned u = __builtin_bit_cast(unsigned, f);
    u += 0x7FFFu + ((u >> 16) & 1u);
    return (unsigned short)(u >> 16);
}
__device__ inline float bf2f(unsigned short b) {
    unsigned u = (unsigned)b << 16;
    return __builtin_bit_cast(float, u);
}

// ---------------------------------------------------------------------------
// K1 (level-1, deterministic, R13-proven): tile blocks [0,391) sort 2048
// edges into 98 live 512-node bins; fixed per-(tile,bin) segments of CAPT
// slots + plain-store counts (TRANSPOSED: counts[bucket][tile] so K2 reads
// contiguously). No global atomics, no zero-init anywhere. Conversion
// blocks convert x -> xb bf16 and W1/W2 -> bf16 transposed [n][k].
// Entry packing: (row<<16)|col.
// ---------------------------------------------------------------------------
__global__ __launch_bounds__(1024) void bin_prep(
    const int* __restrict__ row, const int* __restrict__ col,
    int* __restrict__ counts, int* __restrict__ csr,
    const float* __restrict__ x, unsigned short* __restrict__ xb,
    const float* __restrict__ W1, unsigned short* __restrict__ w1t,
    const float* __restrict__ W2, unsigned short* __restrict__ w2t)
{
    int t = threadIdx.x;
    if (blockIdx.x >= NBB) {            // ---- conversion blocks ----
        int tid = (blockIdx.x - NBB) * 1024 + t;
        if (tid < 800000) {                      // x quads -> bf16
            float4 v = ((const float4*)x)[tid];
            ushort4v o;
            o.x = f2bf(v.x); o.y = f2bf(v.y); o.z = f2bf(v.z); o.w = f2bf(v.w);
            ((ushort4v*)xb)[tid] = o;
        } else {
            int i = tid - 800000;
            if (i < D * H) {                     // W1[k][n] -> w1t[n*64+k]
                int k = i >> 7, n = i & 127;
                w1t[n * D + k] = f2bf(W1[i]);
            } else if (i < 2 * D * H) {          // W2[k][n] -> w2t[n*128+k]
                int j = i - D * H;
                int k = j >> 6, n = j & 63;
                w2t[n * H + k] = f2bf(W2[j]);
            }
        }
        return;
    }

    // ---- tile blocks: LDS counting sort, 2048 entries, 98 live bins ----
    __shared__ int cnt[NBPAD];      // histogram, later local cursor
    __shared__ int loffs[NBPAD];
    __shared__ int sorted[BT];      // 8 KB
    __shared__ int wsum[2];

    int lane = t & 63;
    if (t < NBPAD) cnt[t] = 0;
    __syncthreads();

    int base = blockIdx.x * BT;
    int ia = base + t, ib = ia + 1024;
    int ca = min(ia, N_EDGES - 1), cb2 = min(ib, N_EDGES - 1);
    unsigned ra = (unsigned)row[ca], rb = (unsigned)row[cb2];  // batched
    unsigned ka = (unsigned)col[ca], kb = (unsigned)col[cb2];  // batched
    bool va = ia < N_EDGES, vb = ib < N_EDGES;
    if (va) atomicAdd(&cnt[ra >> 9], 1);
    if (vb) atomicAdd(&cnt[rb >> 9], 1);
    __syncthreads();

    // exclusive scan over 128 padded bins (2 waves)
    int v = 0, incl = 0;
    if (t < NBPAD) {
        v = cnt[t];
        incl = v;
        #pragma unroll
        for (int d = 1; d < 64; d <<= 1) {
            int y = __shfl_up(incl, d);
            if (lane >= d) incl += y;
        }
        if (lane == 63) wsum[t >> 6] = incl;
    }
    __syncthreads();
    if (t < NBPAD) {
        loffs[t] = incl - v + ((t >= 64) ? wsum[0] : 0);
        if (t < NLIVE) counts[(size_t)t * NBB + blockIdx.x] = min(v, CAPT);
    }
    __syncthreads();

    if (t < NBPAD) cnt[t] = 0;      // reuse as local cursor
    __syncthreads();

    if (va) { int b = (int)(ra >> 9); int lp = atomicAdd(&cnt[b], 1);
              sorted[loffs[b] + lp] = (int)((ra << 16) | ka); }
    if (vb) { int b = (int)(rb >> 9); int lp = atomicAdd(&cnt[b], 1);
              sorted[loffs[b] + lp] = (int)((rb << 16) | kb); }
    __syncthreads();

    int nloc = min(BT, N_EDGES - base);
    for (int i = t; i < nloc; i += 1024) {
        unsigned en = (unsigned)sorted[i];
        int b = (int)(en >> 25);                 // row>>9
        int rel = i - loffs[b];
        if (rel < CAPT)
            csr[((size_t)blockIdx.x * NLIVE + b) * CAPT + rel] = (int)en;
    }
}

// ---------------------------------------------------------------------------
// K2 (fused subsort + gather + MLP): block = (bucket, eighth) = 64 nodes;
// 784 blocks x 512 threads, ~37 KB LDS -> 4 blocks/CU (launch_bounds 512,8).
// Replaces R13's K2+K3: no csr2 global round-trip, no redundant re-sort.
//  A) scan the bucket's counts-guided segments (coalesced predicated reads,
//     8x amplification ~ 64 MB L2 total -- cheap), staging this eighth's
//     ~1024 entries + 64-bin hist in one pass
//  B) wave-0 scan of 64 bins  C) place -> per-node col lists
//  D) half-wave register gather from bf16 xb (proven), 8 waves x 8 nodes
//  E) MFMA MLP on waves 0..3 (16 nodes each), weights from global (L1-hot)
// ---------------------------------------------------------------------------
__global__ __launch_bounds__(512, 8) void sub_gather_mlp(
    const float* __restrict__ x, const unsigned short* __restrict__ xb,
    const int* __restrict__ counts, const int* __restrict__ csr,
    const unsigned short* __restrict__ w1t, const float* __restrict__ b1,
    const unsigned short* __restrict__ w2t, const float* __restrict__ b2,
    const float* __restrict__ eps, float* __restrict__ out)
{
    __shared__ int tcnt[NBB];                    // 1.56 KB
    __shared__ int stage[STG];                   // 5.6 KB
    __shared__ unsigned short scol[STG];         // 2.8 KB
    __shared__ int cnt64[64], offs[65], curs[64];
    __shared__ int nstage;
    __shared__ unsigned short HB[64][72];        // 9.2 KB
    __shared__ unsigned short HID[4][16][136];   // 17.4 KB

    int t = threadIdx.x, lane = t & 63, wid = t >> 6;   // 8 waves
    int bucket = blockIdx.x >> 3, eighth = blockIdx.x & 7;

    if (t < 64) cnt64[t] = 0;
    if (t == 0) nstage = 0;
    for (int i = t; i < NBB; i += 512) tcnt[i] = counts[(size_t)bucket * NBB + i];
    __syncthreads();

    // ---- A: filter-scan segments; stage + hist in one pass ----
    for (int s = t; s < NBB * CAPT; s += 512) {
        int tl = s / CAPT, slot = s - tl * CAPT;     // const-div -> magic mul
        if (slot < tcnt[tl]) {
            int e = csr[((size_t)tl * NLIVE + bucket) * CAPT + slot];
            int loc9 = (int)(((unsigned)e >> 16) & 511u);
            if ((loc9 >> 6) == eighth) {
                int p = atomicAdd(&nstage, 1);
                if (p < STG) stage[p] = e;
                atomicAdd(&cnt64[loc9 & 63], 1);
            }
        }
    }
    __syncthreads();

    // ---- B: scan 64 bins (wave 0) ----
    if (t < 64) {
        int v = cnt64[t];
        int incl = v;
        #pragma unroll
        for (int d = 1; d < 64; d <<= 1) {
            int y = __shfl_up(incl, d);
            if (lane >= d) incl += y;
        }
        offs[t] = incl - v;
        curs[t] = incl - v;
        if (t == 63) offs[64] = incl;
    }
    __syncthreads();

    // ---- C: place -> per-node col lists (LDS only) ----
    int nst = min(nstage, STG);
    for (int i = t; i < nst; i += 512) {
        int e = stage[i];
        int nl = (int)(((unsigned)e >> 16) & 63u);
        int p = atomicAdd(&curs[nl], 1);
        if (p < STG) scol[p] = (unsigned short)(e & 0xFFFF);
    }
    __syncthreads();

    // ---- D: register gather: wave wid owns local nodes wid*8..wid*8+7 ----
    float ep = 1.0f + eps[0];
    int half = lane >> 5, fl = lane & 31;        // feature pair 2fl, 2fl+1
    #pragma unroll 1
    for (int nn = 0; nn < 8; ++nn) {
        int nl = wid * 8 + nn;                   // 0..63
        int node = bucket * 512 + eighth * 64 + nl;
        int jb = min(offs[nl], STG), je = min(offs[nl + 1], STG);
        float s0a = 0.f, s1a = 0.f, s0b = 0.f, s1b = 0.f;
        float s0c = 0.f, s1c = 0.f, s0d = 0.f, s1d = 0.f;
        int j = jb;
        for (; j + 8 <= je; j += 8) {
            int c0 = scol[j + half];
            int c1 = scol[j + 2 + half];
            int c2 = scol[j + 4 + half];
            int c3 = scol[j + 6 + half];
            ushort2 p0 = *(const ushort2*)&xb[c0 * D + 2 * fl];
            ushort2 p1 = *(const ushort2*)&xb[c1 * D + 2 * fl];
            ushort2 p2 = *(const ushort2*)&xb[c2 * D + 2 * fl];
            ushort2 p3 = *(const ushort2*)&xb[c3 * D + 2 * fl];
            s0a += bf2f(p0.x); s1a += bf2f(p0.y);
            s0b += bf2f(p1.x); s1b += bf2f(p1.y);
            s0c += bf2f(p2.x); s1c += bf2f(p2.y);
            s0d += bf2f(p3.x); s1d += bf2f(p3.y);
        }
        for (; j < je; j += 2) {
            if (j + half < je) {
                int c = scol[j + half];
                ushort2 p = *(const ushort2*)&xb[c * D + 2 * fl];
                s0a += bf2f(p.x); s1a += bf2f(p.y);
            }
        }
        float s0 = (s0a + s0b) + (s0c + s0d);
        float s1 = (s1a + s1b) + (s1c + s1d);
        s0 += __shfl_xor(s0, 32);
        s1 += __shfl_xor(s1, 32);
        if (half == 0) {
            float2 xv = {0.f, 0.f};
            if (node < N_NODES) xv = *(const float2*)&x[(size_t)node * D + 2 * fl];
            ushort2 o;
            o.x = f2bf(fmaf(ep, xv.x, s0));
            o.y = f2bf(fmaf(ep, xv.y, s1));
            *(ushort2*)&HB[nl][2 * fl] = o;
        }
    }
    __syncthreads();   // HB written by all 8 waves, read by waves 0..3

    // ---- E: MLP on waves 0..3 (16 nodes each); weights from global ----
    if (wid < 4) {
        int m = lane & 15, q = lane >> 4;
        short8 a0 = *(const short8*)&HB[wid * 16 + m][q * 8];
        short8 a1 = *(const short8*)&HB[wid * 16 + m][32 + q * 8];

        #pragma unroll
        for (int nt = 0; nt < 8; ++nt) {
            float bias = b1[nt * 16 + m];
            floatx4 acc = {bias, bias, bias, bias};
            short8 w0 = *(const short8*)&w1t[(nt * 16 + m) * D + q * 8];
            short8 w1 = *(const short8*)&w1t[(nt * 16 + m) * D + 32 + q * 8];
            acc = __builtin_amdgcn_mfma_f32_16x16x32_bf16(a0, w0, acc, 0, 0, 0);
            acc = __builtin_amdgcn_mfma_f32_16x16x32_bf16(a1, w1, acc, 0, 0, 0);
            #pragma unroll
            for (int r = 0; r < 4; ++r) {
                float hv = fmaxf(acc[r], 0.0f);
                HID[wid][q * 4 + r][nt * 16 + m] = f2bf(hv);
            }
        }
        // wave-internal LDS RAW: compiler inserts lgkmcnt waits; no barrier

        short8 ha[4];
        #pragma unroll
        for (int kc2 = 0; kc2 < 4; ++kc2)
            ha[kc2] = *(const short8*)&HID[wid][m][kc2 * 32 + q * 8];

        #pragma unroll
        for (int nt2 = 0; nt2 < 4; ++nt2) {
            float bias = b2[nt2 * 16 + m];
            floatx4 acc = {bias, bias, bias, bias};
            #pragma unroll
            for (int kc2 = 0; kc2 < 4; ++kc2) {
                short8 w = *(const short8*)&w2t[(nt2 * 16 + m) * H + kc2 * 32 + q * 8];
                acc = __builtin_amdgcn_mfma_f32_16x16x32_bf16(ha[kc2], w, acc, 0, 0, 0);
            }
            #pragma unroll
            for (int r = 0; r < 4; ++r) {
                int nn2 = bucket * 512 + eighth * 64 + wid * 16 + q * 4 + r;
                if (nn2 < N_NODES) out[(size_t)nn2 * D + nt2 * 16 + m] = acc[r];
            }
        }
    }
}

// ---------------------------------------------------------------------------
extern "C" void kernel_launch(void* const* d_in, const int* in_sizes, int n_in,
                              void* d_out, int out_size, void* d_ws, size_t ws_size,
                              hipStream_t stream) {
    const float* x   = (const float*)d_in[0];
    const int*   ei  = (const int*)  d_in[1];   // [2, 800000] int32
    const float* W1  = (const float*)d_in[2];
    const float* b1  = (const float*)d_in[3];
    const float* W2  = (const float*)d_in[4];
    const float* b2  = (const float*)d_in[5];
    const float* eps = (const float*)d_in[6];
    float* out = (float*)d_out;

    // ws (~14.6 MB): xb | w1t | w2t | csr(segments) | counts (transposed)
    unsigned short* xb  = (unsigned short*)d_ws;          // 3.2M bf16, 6.4 MB
    unsigned short* w1t = xb + (size_t)N_NODES * D;       // 8192
    unsigned short* w2t = w1t + D * H;                    // 8192
    int* csr    = (int*)(w2t + D * H);                    // 391*98*52, 7.97 MB
    int* counts = csr + (size_t)NBB * NLIVE * CAPT;       // 98*391, 153 KB

    const int* row = ei;
    const int* col = ei + N_EDGES;

    // 2 dispatches, no memset, no global atomics in K1, no csr2 round-trip.
    bin_prep<<<NBB + CVB, 1024, 0, stream>>>(row, col, counts, csr,
                                             x, xb, W1, w1t, W2, w2t);
    sub_gather_mlp<<<NLIVE * 8, 512, 0, stream>>>(x, xb, counts, csr,
                                                  w1t, b1, w2t, b2, eps, out);
}

// Round 15
// 119.274 us; speedup vs baseline: 1.1404x; 1.1404x over previous
//
#include <hip/hip_runtime.h>

#define N_NODES 50000
#define N_EDGES 800000
#define D 64
#define H 128
#define NLIVE 98       // live 512-node buckets = ceil(50000/512)
#define NBPAD 128      // padded bin arrays for scans
#define BT 2048        // edges per level-1 tile
#define NBB 391        // ceil(N_EDGES/BT)
#define CAPT 52        // slots per (tile,bucket) segment (mean 21, sigma 4.6)
#define NT8 49         // tiles per eighth
#define STG 1280       // K2 stage cap (mean 1028, sigma 32)
#define SCAP2 352      // csr2 slots per (bucket,sub) (mean 256, sigma 16)
#define CVB 798        // conversion blocks: ceil((800000+16384)/1024)

typedef __attribute__((ext_vector_type(8))) short  short8;   // 8 bf16
typedef __attribute__((ext_vector_type(4))) float  floatx4;
typedef __attribute__((ext_vector_type(4))) unsigned short ushort4v;

__device__ inline unsigned short f2bf(float f) {   // round-to-nearest-even
    unsigned u = __builtin_bit_cast(unsigned, f);
    u += 0x7FFFu + ((u >> 16) & 1u);
    return (unsigned short)(u >> 16);
}
__device__ inline float bf2f(unsigned short b) {
    unsigned u = (unsigned)b << 16;
    return __builtin_bit_cast(float, u);
}

// ---------------------------------------------------------------------------
// K1 (R13-proven, unchanged): tile blocks [0,391) sort 2048 edges into 98
// live 512-node bins, fixed per-(tile,bin) segments + plain-store counts.
// No global atomics, no zero-init. Conversion blocks convert x -> xb bf16,
// W1/W2 -> bf16 transposed [n][k]; block NBB also zeroes cursor2 for K2.
// ---------------------------------------------------------------------------
__global__ __launch_bounds__(1024) void bin_prep(
    const int* __restrict__ row, const int* __restrict__ col,
    int* __restrict__ counts, int* __restrict__ csr,
    int* __restrict__ cursor2,
    const float* __restrict__ x, unsigned short* __restrict__ xb,
    const float* __restrict__ W1, unsigned short* __restrict__ w1t,
    const float* __restrict__ W2, unsigned short* __restrict__ w2t)
{
    int t = threadIdx.x;
    if (blockIdx.x >= NBB) {            // ---- conversion blocks ----
        int cb = blockIdx.x - NBB;
        if (cb == 0)
            for (int i = t; i < NLIVE * 32; i += 1024) cursor2[i] = 0;
        int tid = cb * 1024 + t;
        if (tid < 800000) {                      // x quads -> bf16
            float4 v = ((const float4*)x)[tid];
            ushort4v o;
            o.x = f2bf(v.x); o.y = f2bf(v.y); o.z = f2bf(v.z); o.w = f2bf(v.w);
            ((ushort4v*)xb)[tid] = o;
        } else {
            int i = tid - 800000;
            if (i < D * H) {                     // W1[k][n] -> w1t[n*64+k]
                int k = i >> 7, n = i & 127;
                w1t[n * D + k] = f2bf(W1[i]);
            } else if (i < 2 * D * H) {          // W2[k][n] -> w2t[n*128+k]
                int j = i - D * H;
                int k = j >> 6, n = j & 63;
                w2t[n * H + k] = f2bf(W2[j]);
            }
        }
        return;
    }

    // ---- tile blocks: LDS counting sort, 2048 entries, 98 live bins ----
    __shared__ int cnt[NBPAD];
    __shared__ int loffs[NBPAD];
    __shared__ int sorted[BT];      // 8 KB
    __shared__ int wsum[2];

    int lane = t & 63;
    if (t < NBPAD) cnt[t] = 0;
    __syncthreads();

    int base = blockIdx.x * BT;
    int ia = base + t, ib = ia + 1024;
    int ca = min(ia, N_EDGES - 1), cb2 = min(ib, N_EDGES - 1);
    unsigned ra = (unsigned)row[ca], rb = (unsigned)row[cb2];
    unsigned ka = (unsigned)col[ca], kb = (unsigned)col[cb2];
    bool va = ia < N_EDGES, vb = ib < N_EDGES;
    if (va) atomicAdd(&cnt[ra >> 9], 1);
    if (vb) atomicAdd(&cnt[rb >> 9], 1);
    __syncthreads();

    int v = 0, incl = 0;
    if (t < NBPAD) {
        v = cnt[t];
        incl = v;
        #pragma unroll
        for (int d = 1; d < 64; d <<= 1) {
            int y = __shfl_up(incl, d);
            if (lane >= d) incl += y;
        }
        if (lane == 63) wsum[t >> 6] = incl;
    }
    __syncthreads();
    if (t < NBPAD) {
        loffs[t] = incl - v + ((t >= 64) ? wsum[0] : 0);
        if (t < NLIVE) counts[blockIdx.x * NLIVE + t] = min(v, CAPT);
    }
    __syncthreads();

    if (t < NBPAD) cnt[t] = 0;
    __syncthreads();

    if (va) { int b = (int)(ra >> 9); int lp = atomicAdd(&cnt[b], 1);
              sorted[loffs[b] + lp] = (int)((ra << 16) | ka); }
    if (vb) { int b = (int)(rb >> 9); int lp = atomicAdd(&cnt[b], 1);
              sorted[loffs[b] + lp] = (int)((rb << 16) | kb); }
    __syncthreads();

    int nloc = min(BT, N_EDGES - base);
    for (int i = t; i < nloc; i += 1024) {
        unsigned en = (unsigned)sorted[i];
        int b = (int)(en >> 25);
        int rel = i - loffs[b];
        if (rel < CAPT)
            csr[((size_t)blockIdx.x * NLIVE + b) * CAPT + rel] = (int)en;
    }
}

// ---------------------------------------------------------------------------
// K2 (R13 + ballot-append): block = (bucket, eighth). Reads counts-guided
// segments for its 49 tiles ONCE (~1030 entries), ballot-aggregated append
// (one leader atomic per wave-chunk, vs R13's ~1030 serialized same-address
// LDS atomics), 32-bin sort, claims csr2 bases, coalesced write-out.
// ---------------------------------------------------------------------------
__global__ __launch_bounds__(256, 8) void subsort(
    const int* __restrict__ counts, const int* __restrict__ csr,
    int* __restrict__ cursor2, int* __restrict__ csr2)
{
    __shared__ int tcnt[NT8];
    __shared__ int stage[STG];                  // 5 KB
    __shared__ int sorted2[STG];                // 5 KB
    __shared__ int cnt32[32], loffs[32], gbase[32], curs[32];
    __shared__ int nstage;

    int t = threadIdx.x, lane = t & 63;
    int bucket = blockIdx.x >> 3, q = blockIdx.x & 7;
    int tbeg = q * NT8;
    int ntile = min(NT8, NBB - tbeg);

    if (t < 32) cnt32[t] = 0;
    if (t == 0) nstage = 0;
    if (t < ntile) tcnt[t] = counts[(size_t)(tbeg + t) * NLIVE + bucket];
    __syncthreads();

    // stage + hist; ballot-aggregated append
    for (int s = t; s < ntile * CAPT; s += 256) {
        int tl = s / CAPT, slot = s - tl * CAPT;
        bool valid = slot < tcnt[tl];
        int e = 0;
        if (valid) e = csr[((size_t)(tbeg + tl) * NLIVE + bucket) * CAPT + slot];
        unsigned long long mk = __ballot(valid);
        if (mk) {
            int ldr = __ffsll((long long)mk) - 1;
            int pb = 0;
            if (lane == ldr) pb = atomicAdd(&nstage, __popcll(mk));
            pb = __shfl(pb, ldr);
            if (valid) {
                int p = pb + __popcll(mk & ((1ull << lane) - 1ull));
                if (p < STG) stage[p] = e;
                atomicAdd(&cnt32[((unsigned)e >> 20) & 31u], 1);
            }
        }
    }
    __syncthreads();

    int nst = min(nstage, STG);
    if (t < 32) {                                // scan 32 bins + claim bases
        int v = cnt32[t];
        int incl = v;
        #pragma unroll
        for (int d = 1; d < 32; d <<= 1) {
            int y = __shfl_up(incl, d);
            if (lane >= d) incl += y;
        }
        loffs[t] = incl - v;
        curs[t]  = incl - v;
        gbase[t] = v ? atomicAdd(&cursor2[bucket * 32 + t], v) : 0;
    }
    __syncthreads();

    for (int i = t; i < nst; i += 256) {         // place by sub
        int e = stage[i];
        int sub = (int)(((unsigned)e >> 20) & 31u);
        int p = atomicAdd(&curs[sub], 1);
        sorted2[min(p, STG - 1)] = e;
    }
    __syncthreads();

    for (int i = t; i < nst; i += 256) {         // coalesced write-out
        unsigned en = (unsigned)sorted2[i];
        int sub = (int)((en >> 20) & 31u);
        int rel = gbase[sub] + (i - loffs[sub]);
        if (rel < SCAP2)
            csr2[((size_t)bucket * 32 + sub) * SCAP2 + rel] =
                (int)(en & 0xFFFFFu);            // (nl<<16)|col
    }
}

// ---------------------------------------------------------------------------
// K3 (R13 + quarter-wave gather): block = (bucket,sub) = 16 nodes; 3136
// blocks, ~9 KB LDS, launch_bounds(256,8). 16-bin sort of own list, then
// QUARTER-WAVE gather: 16 lanes x ushort4 (8B) = one 128B line per entry,
// 4 entries per load instr (2x fewer instrs, 2x more in flight than R13's
// half-wave ushort2); reduce via shfl_xor(16,32); lanes 0-15 add (1+eps)x
// (float4) and write HB row (ushort4). Wave-0 MFMA MLP unchanged.
// ---------------------------------------------------------------------------
__global__ __launch_bounds__(256, 8) void gather_mlp(
    const float* __restrict__ x, const unsigned short* __restrict__ xb,
    const int* __restrict__ cursor2, const int* __restrict__ csr2,
    const unsigned short* __restrict__ w1t, const float* __restrict__ b1,
    const unsigned short* __restrict__ w2t, const float* __restrict__ b2,
    const float* __restrict__ eps, float* __restrict__ out)
{
    __shared__ int ent[SCAP2];                   // 1.4 KB
    __shared__ unsigned short scol[SCAP2];       // 0.7 KB
    __shared__ int cnt16[16], offs[17], curs[16];
    __shared__ unsigned short HB[16][72];        // 2.3 KB
    __shared__ unsigned short HID[16][136];      // 4.4 KB (wave-0 private)

    int t = threadIdx.x, lane = t & 63, wid = t >> 6;
    int bs = blockIdx.x;
    int bucket = bs >> 5, sub = bs & 31;

    if (t < 16) cnt16[t] = 0;
    __syncthreads();

    int n2 = min(cursor2[bs], SCAP2);
    const int* src = csr2 + (size_t)bs * SCAP2;

    for (int i = t; i < n2; i += 256) {          // stage + hist in one pass
        int e = src[i];
        ent[i] = e;
        atomicAdd(&cnt16[((unsigned)e >> 16) & 15u], 1);
    }
    __syncthreads();

    if (t < 16) {                                // scan 16 bins
        int v = cnt16[t];
        int incl = v;
        #pragma unroll
        for (int d = 1; d < 16; d <<= 1) {
            int y = __shfl_up(incl, d);
            if (lane >= d) incl += y;
        }
        offs[t] = incl - v;
        curs[t] = incl - v;
        if (t == 15) offs[16] = incl;
    }
    __syncthreads();

    for (int i = t; i < n2; i += 256) {          // place (LDS only)
        int e = ent[i];
        int nl = (int)(((unsigned)e >> 16) & 15u);
        int p = atomicAdd(&curs[nl], 1);
        scol[p] = (unsigned short)(e & 0xFFFF);
    }
    __syncthreads();

    // ---- quarter-wave register gather: wave wid owns nodes wid*4..+3 ----
    float ep = 1.0f + eps[0];
    int ent4 = lane >> 4;          // entry slot 0..3 within the wave group
    int fl = lane & 15;            // feature nibble: features 4fl..4fl+3
    #pragma unroll 1
    for (int nn = 0; nn < 4; ++nn) {
        int nl = wid * 4 + nn;                   // 0..15
        int node = bucket * 512 + sub * 16 + nl;
        int jb = offs[nl], je = offs[nl + 1];
        float a0 = 0.f, a1 = 0.f, a2 = 0.f, a3 = 0.f;
        float b0v = 0.f, b1v = 0.f, b2v = 0.f, b3v = 0.f;
        for (int j = jb; j < je; j += 8) {
            int i0 = j + ent4, i1 = j + 4 + ent4;
            bool v0 = i0 < je, v1 = i1 < je;
            int c0 = scol[v0 ? i0 : jb];
            int c1 = scol[v1 ? i1 : jb];
            ushort4v p0 = *(const ushort4v*)&xb[c0 * D + 4 * fl];
            ushort4v p1 = *(const ushort4v*)&xb[c1 * D + 4 * fl];
            if (v0) { a0 += bf2f(p0.x); a1 += bf2f(p0.y);
                      a2 += bf2f(p0.z); a3 += bf2f(p0.w); }
            if (v1) { b0v += bf2f(p1.x); b1v += bf2f(p1.y);
                      b2v += bf2f(p1.z); b3v += bf2f(p1.w); }
        }
        float s0 = a0 + b0v, s1 = a1 + b1v, s2 = a2 + b2v, s3 = a3 + b3v;
        s0 += __shfl_xor(s0, 16); s1 += __shfl_xor(s1, 16);
        s2 += __shfl_xor(s2, 16); s3 += __shfl_xor(s3, 16);
        s0 += __shfl_xor(s0, 32); s1 += __shfl_xor(s1, 32);
        s2 += __shfl_xor(s2, 32); s3 += __shfl_xor(s3, 32);
        if (lane < 16) {
            float4 xv = {0.f, 0.f, 0.f, 0.f};
            if (node < N_NODES) xv = *(const float4*)&x[(size_t)node * D + 4 * fl];
            ushort4v o;
            o.x = f2bf(fmaf(ep, xv.x, s0));
            o.y = f2bf(fmaf(ep, xv.y, s1));
            o.z = f2bf(fmaf(ep, xv.z, s2));
            o.w = f2bf(fmaf(ep, xv.w, s3));
            *(ushort4v*)&HB[nl][4 * fl] = o;
        }
    }
    __syncthreads();   // HB written by all waves, read by wave 0

    // ---- MLP: wave 0 owns the 16 nodes; weights from global (L1-hot) ----
    if (wid == 0) {
        int m = lane & 15, q = lane >> 4;
        short8 a0 = *(const short8*)&HB[m][q * 8];
        short8 a1 = *(const short8*)&HB[m][32 + q * 8];

        #pragma unroll
        for (int nt = 0; nt < 8; ++nt) {
            float bias = b1[nt * 16 + m];
            floatx4 acc = {bias, bias, bias, bias};
            short8 w0 = *(const short8*)&w1t[(nt * 16 + m) * D + q * 8];
            short8 w1 = *(const short8*)&w1t[(nt * 16 + m) * D + 32 + q * 8];
            acc = __builtin_amdgcn_mfma_f32_16x16x32_bf16(a0, w0, acc, 0, 0, 0);
            acc = __builtin_amdgcn_mfma_f32_16x16x32_bf16(a1, w1, acc, 0, 0, 0);
            #pragma unroll
            for (int r = 0; r < 4; ++r) {
                float hv = fmaxf(acc[r], 0.0f);
                HID[q * 4 + r][nt * 16 + m] = f2bf(hv);
            }
        }
        // wave-internal LDS RAW: compiler inserts lgkmcnt waits; no barrier

        short8 ha[4];
        #pragma unroll
        for (int kc2 = 0; kc2 < 4; ++kc2)
            ha[kc2] = *(const short8*)&HID[m][kc2 * 32 + q * 8];

        #pragma unroll
        for (int nt2 = 0; nt2 < 4; ++nt2) {
            float bias = b2[nt2 * 16 + m];
            floatx4 acc = {bias, bias, bias, bias};
            #pragma unroll
            for (int kc2 = 0; kc2 < 4; ++kc2) {
                short8 w = *(const short8*)&w2t[(nt2 * 16 + m) * H + kc2 * 32 + q * 8];
                acc = __builtin_amdgcn_mfma_f32_16x16x32_bf16(ha[kc2], w, acc, 0, 0, 0);
            }
            #pragma unroll
            for (int r = 0; r < 4; ++r) {
                int nn2 = bucket * 512 + sub * 16 + q * 4 + r;
                if (nn2 < N_NODES) out[(size_t)nn2 * D + nt2 * 16 + m] = acc[r];
            }
        }
    }
}

// ---------------------------------------------------------------------------
extern "C" void kernel_launch(void* const* d_in, const int* in_sizes, int n_in,
                              void* d_out, int out_size, void* d_ws, size_t ws_size,
                              hipStream_t stream) {
    const float* x   = (const float*)d_in[0];
    const int*   ei  = (const int*)  d_in[1];   // [2, 800000] int32
    const float* W1  = (const float*)d_in[2];
    const float* b1  = (const float*)d_in[3];
    const float* W2  = (const float*)d_in[4];
    const float* b2  = (const float*)d_in[5];
    const float* eps = (const float*)d_in[6];
    float* out = (float*)d_out;

    // ws (~19.0 MB): xb | w1t | w2t | csr(segments) | counts | csr2 | cursor2
    unsigned short* xb  = (unsigned short*)d_ws;          // 3.2M bf16, 6.4 MB
    unsigned short* w1t = xb + (size_t)N_NODES * D;       // 8192
    unsigned short* w2t = w1t + D * H;                    // 8192
    int* csr     = (int*)(w2t + D * H);                   // 391*98*52, 7.97 MB
    int* counts  = csr + (size_t)NBB * NLIVE * CAPT;      // 391*98, 153 KB
    int* csr2    = counts + (size_t)NBB * NLIVE;          // 3136*352, 4.42 MB
    int* cursor2 = csr2 + (size_t)NLIVE * 32 * SCAP2;     // 3136

    const int* row = ei;
    const int* col = ei + N_EDGES;

    bin_prep<<<NBB + CVB, 1024, 0, stream>>>(row, col, counts, csr, cursor2,
                                             x, xb, W1, w1t, W2, w2t);
    subsort<<<NLIVE * 8, 256, 0, stream>>>(counts, csr, cursor2, csr2);
    gather_mlp<<<NLIVE * 32, 256, 0, stream>>>(x, xb, cursor2, csr2,
                                               w1t, b1, w2t, b2, eps, out);
}

// Round 16
// 118.431 us; speedup vs baseline: 1.1485x; 1.0071x over previous
//
#include <hip/hip_runtime.h>

#define N_NODES 50000
#define N_EDGES 800000
#define D 64
#define H 128
#define NLIVE 98       // live 512-node buckets = ceil(50000/512)
#define NBPAD 128      // padded bin arrays for scans
#define BT 2048        // edges per level-1 tile
#define NBB 391        // ceil(N_EDGES/BT)
#define CAPT 64        // slots per (tile,bucket) segment (mean 21; 256B-aligned, /CAPT = shift)
#define NT8 49         // tiles per eighth
#define STG 1280       // K2 stage cap (mean 1020, sigma 32)
#define SCAP2 352      // csr2 slots per (bucket,sub) (mean 256, sigma 16)
#define NSUBB 784      // K2 subsort blocks (98*8)
#define CVB 3189       // conversion blocks in K2 grid: ceil(816384/256)

typedef __attribute__((ext_vector_type(8))) short  short8;   // 8 bf16
typedef __attribute__((ext_vector_type(4))) float  floatx4;
typedef __attribute__((ext_vector_type(4))) unsigned short ushort4v;

__device__ inline unsigned short f2bf(float f) {   // round-to-nearest-even
    unsigned u = __builtin_bit_cast(unsigned, f);
    u += 0x7FFFu + ((u >> 16) & 1u);
    return (unsigned short)(u >> 16);
}
__device__ inline float bf2f(unsigned short b) {
    unsigned u = (unsigned)b << 16;
    return __builtin_bit_cast(float, u);
}

// ---------------------------------------------------------------------------
// K1 (level-1 sort only): 782-wide critical path. Tile blocks [0,391) use
// 512 threads x 4 entries (4-deep batched row+col loads held in registers
// across hist->place). Fixed per-(tile,bin) segments (CAPT=64 -> 256B
// aligned) + plain-store counts. Block NBB zeroes cursor2 for K2.
// Conversion work moved to K2's grid (feeds only K3).
// Entry packing: (row<<16)|col.
// ---------------------------------------------------------------------------
__global__ __launch_bounds__(512) void bin_prep(
    const int* __restrict__ row, const int* __restrict__ col,
    int* __restrict__ counts, int* __restrict__ csr,
    int* __restrict__ cursor2)
{
    int t = threadIdx.x;
    if (blockIdx.x == NBB) {            // ---- cursor2 zeroing block ----
        for (int i = t; i < NLIVE * 32; i += 512) cursor2[i] = 0;
        return;
    }

    // ---- tile blocks: LDS counting sort, 2048 entries, 98 live bins ----
    __shared__ int cnt[NBPAD];
    __shared__ int loffs[NBPAD];
    __shared__ int sorted[BT];      // 8 KB
    __shared__ int wsum[2];

    int lane = t & 63;
    if (t < NBPAD) cnt[t] = 0;
    __syncthreads();

    int base = blockIdx.x * BT;
    int ia = base + t, ib = ia + 512, ic = ia + 1024, id = ia + 1536;
    int ca = min(ia, N_EDGES - 1), cb = min(ib, N_EDGES - 1);
    int cc = min(ic, N_EDGES - 1), cd = min(id, N_EDGES - 1);
    unsigned ra = (unsigned)row[ca], rb = (unsigned)row[cb];
    unsigned rc = (unsigned)row[cc], rd = (unsigned)row[cd];
    unsigned ka = (unsigned)col[ca], kb = (unsigned)col[cb];
    unsigned kc = (unsigned)col[cc], kd = (unsigned)col[cd];
    bool va = ia < N_EDGES, vb = ib < N_EDGES;
    bool vc = ic < N_EDGES, vd = id < N_EDGES;
    if (va) atomicAdd(&cnt[ra >> 9], 1);
    if (vb) atomicAdd(&cnt[rb >> 9], 1);
    if (vc) atomicAdd(&cnt[rc >> 9], 1);
    if (vd) atomicAdd(&cnt[rd >> 9], 1);
    __syncthreads();

    int v = 0, incl = 0;
    if (t < NBPAD) {
        v = cnt[t];
        incl = v;
        #pragma unroll
        for (int d = 1; d < 64; d <<= 1) {
            int y = __shfl_up(incl, d);
            if (lane >= d) incl += y;
        }
        if (lane == 63) wsum[t >> 6] = incl;
    }
    __syncthreads();
    if (t < NBPAD) {
        loffs[t] = incl - v + ((t >= 64) ? wsum[0] : 0);
        if (t < NLIVE) counts[blockIdx.x * NLIVE + t] = min(v, CAPT);
    }
    __syncthreads();

    if (t < NBPAD) cnt[t] = 0;      // reuse as local cursor
    __syncthreads();

    if (va) { int b = (int)(ra >> 9); int lp = atomicAdd(&cnt[b], 1);
              sorted[loffs[b] + lp] = (int)((ra << 16) | ka); }
    if (vb) { int b = (int)(rb >> 9); int lp = atomicAdd(&cnt[b], 1);
              sorted[loffs[b] + lp] = (int)((rb << 16) | kb); }
    if (vc) { int b = (int)(rc >> 9); int lp = atomicAdd(&cnt[b], 1);
              sorted[loffs[b] + lp] = (int)((rc << 16) | kc); }
    if (vd) { int b = (int)(rd >> 9); int lp = atomicAdd(&cnt[b], 1);
              sorted[loffs[b] + lp] = (int)((rd << 16) | kd); }
    __syncthreads();

    int nloc = min(BT, N_EDGES - base);
    for (int i = t; i < nloc; i += 512) {
        unsigned en = (unsigned)sorted[i];
        int b = (int)(en >> 25);
        int rel = i - loffs[b];
        if (rel < CAPT)
            csr[((size_t)blockIdx.x * NLIVE + b) * CAPT + rel] = (int)en;
    }
}

// ---------------------------------------------------------------------------
// K2 (subsort + conversion): blocks [0,784) = (bucket, eighth) subsort
// (R15-proven ballot-append structure, CAPT now pow2 so tl = s>>6);
// blocks [784, 784+3189) convert x -> xb bf16 and W1/W2 -> bf16 transposed
// [n][k] (feeds only K3; overlaps subsort's latency bubbles instead of
// extending K1's critical path).
// ---------------------------------------------------------------------------
__global__ __launch_bounds__(256, 8) void subsort_conv(
    const int* __restrict__ counts, const int* __restrict__ csr,
    int* __restrict__ cursor2, int* __restrict__ csr2,
    const float* __restrict__ x, unsigned short* __restrict__ xb,
    const float* __restrict__ W1, unsigned short* __restrict__ w1t,
    const float* __restrict__ W2, unsigned short* __restrict__ w2t)
{
    int t = threadIdx.x;
    if (blockIdx.x >= NSUBB) {          // ---- conversion blocks ----
        int tid = (blockIdx.x - NSUBB) * 256 + t;
        if (tid < 800000) {                      // x quads -> bf16
            float4 v = ((const float4*)x)[tid];
            ushort4v o;
            o.x = f2bf(v.x); o.y = f2bf(v.y); o.z = f2bf(v.z); o.w = f2bf(v.w);
            ((ushort4v*)xb)[tid] = o;
        } else {
            int i = tid - 800000;
            if (i < D * H) {                     // W1[k][n] -> w1t[n*64+k]
                int k = i >> 7, n = i & 127;
                w1t[n * D + k] = f2bf(W1[i]);
            } else if (i < 2 * D * H) {          // W2[k][n] -> w2t[n*128+k]
                int j = i - D * H;
                int k = j >> 6, n = j & 63;
                w2t[n * H + k] = f2bf(W2[j]);
            }
        }
        return;
    }

    __shared__ int tcnt[NT8];
    __shared__ int stage[STG];                  // 5 KB
    __shared__ int sorted2[STG];                // 5 KB
    __shared__ int cnt32[32], loffs[32], gbase[32], curs[32];
    __shared__ int nstage;

    int lane = t & 63;
    int bucket = blockIdx.x >> 3, q = blockIdx.x & 7;
    int tbeg = q * NT8;
    int ntile = min(NT8, NBB - tbeg);

    if (t < 32) cnt32[t] = 0;
    if (t == 0) nstage = 0;
    if (t < ntile) tcnt[t] = counts[(size_t)(tbeg + t) * NLIVE + bucket];
    __syncthreads();

    // stage + hist; ballot-aggregated append (R15-proven)
    for (int s = t; s < ntile * CAPT; s += 256) {
        int tl = s >> 6, slot = s & (CAPT - 1);
        bool valid = slot < tcnt[tl];
        int e = 0;
        if (valid) e = csr[((size_t)(tbeg + tl) * NLIVE + bucket) * CAPT + slot];
        unsigned long long mk = __ballot(valid);
        if (mk) {
            int ldr = __ffsll((long long)mk) - 1;
            int pb = 0;
            if (lane == ldr) pb = atomicAdd(&nstage, __popcll(mk));
            pb = __shfl(pb, ldr);
            if (valid) {
                int p = pb + __popcll(mk & ((1ull << lane) - 1ull));
                if (p < STG) stage[p] = e;
                atomicAdd(&cnt32[((unsigned)e >> 20) & 31u], 1);
            }
        }
    }
    __syncthreads();

    int nst = min(nstage, STG);
    if (t < 32) {                                // scan 32 bins + claim bases
        int v = cnt32[t];
        int incl = v;
        #pragma unroll
        for (int d = 1; d < 32; d <<= 1) {
            int y = __shfl_up(incl, d);
            if (lane >= d) incl += y;
        }
        loffs[t] = incl - v;
        curs[t]  = incl - v;
        gbase[t] = v ? atomicAdd(&cursor2[bucket * 32 + t], v) : 0;
    }
    __syncthreads();

    for (int i = t; i < nst; i += 256) {         // place by sub
        int e = stage[i];
        int sub = (int)(((unsigned)e >> 20) & 31u);
        int p = atomicAdd(&curs[sub], 1);
        sorted2[min(p, STG - 1)] = e;
    }
    __syncthreads();

    for (int i = t; i < nst; i += 256) {         // coalesced write-out
        unsigned en = (unsigned)sorted2[i];
        int sub = (int)((en >> 20) & 31u);
        int rel = gbase[sub] + (i - loffs[sub]);
        if (rel < SCAP2)
            csr2[((size_t)bucket * 32 + sub) * SCAP2 + rel] =
                (int)(en & 0xFFFFFu);            // (nl<<16)|col
    }
}

// ---------------------------------------------------------------------------
// K3 (R15-proven, unchanged): block = (bucket,sub) = 16 nodes; 3136 blocks,
// ~9 KB LDS, launch_bounds(256,8). 16-bin sort of own list, quarter-wave
// ushort4 gather (one 128B line per entry, 4 entries/load-instr), shfl_xor
// (16,32) reduce, wave-0 MFMA MLP with weights from global (L1-hot).
// ---------------------------------------------------------------------------
__global__ __launch_bounds__(256, 8) void gather_mlp(
    const float* __restrict__ x, const unsigned short* __restrict__ xb,
    const int* __restrict__ cursor2, const int* __restrict__ csr2,
    const unsigned short* __restrict__ w1t, const float* __restrict__ b1,
    const unsigned short* __restrict__ w2t, const float* __restrict__ b2,
    const float* __restrict__ eps, float* __restrict__ out)
{
    __shared__ int ent[SCAP2];                   // 1.4 KB
    __shared__ unsigned short scol[SCAP2];       // 0.7 KB
    __shared__ int cnt16[16], offs[17], curs[16];
    __shared__ unsigned short HB[16][72];        // 2.3 KB
    __shared__ unsigned short HID[16][136];      // 4.4 KB (wave-0 private)

    int t = threadIdx.x, lane = t & 63, wid = t >> 6;
    int bs = blockIdx.x;
    int bucket = bs >> 5, sub = bs & 31;

    if (t < 16) cnt16[t] = 0;
    __syncthreads();

    int n2 = min(cursor2[bs], SCAP2);
    const int* src = csr2 + (size_t)bs * SCAP2;

    for (int i = t; i < n2; i += 256) {          // stage + hist in one pass
        int e = src[i];
        ent[i] = e;
        atomicAdd(&cnt16[((unsigned)e >> 16) & 15u], 1);
    }
    __syncthreads();

    if (t < 16) {                                // scan 16 bins
        int v = cnt16[t];
        int incl = v;
        #pragma unroll
        for (int d = 1; d < 16; d <<= 1) {
            int y = __shfl_up(incl, d);
            if (lane >= d) incl += y;
        }
        offs[t] = incl - v;
        curs[t] = incl - v;
        if (t == 15) offs[16] = incl;
    }
    __syncthreads();

    for (int i = t; i < n2; i += 256) {          // place (LDS only)
        int e = ent[i];
        int nl = (int)(((unsigned)e >> 16) & 15u);
        int p = atomicAdd(&curs[nl], 1);
        scol[p] = (unsigned short)(e & 0xFFFF);
    }
    __syncthreads();

    // ---- quarter-wave register gather: wave wid owns nodes wid*4..+3 ----
    float ep = 1.0f + eps[0];
    int ent4 = lane >> 4;          // entry slot 0..3 within the wave group
    int fl = lane & 15;            // feature nibble: features 4fl..4fl+3
    #pragma unroll 1
    for (int nn = 0; nn < 4; ++nn) {
        int nl = wid * 4 + nn;                   // 0..15
        int node = bucket * 512 + sub * 16 + nl;
        int jb = offs[nl], je = offs[nl + 1];
        float a0 = 0.f, a1 = 0.f, a2 = 0.f, a3 = 0.f;
        float b0v = 0.f, b1v = 0.f, b2v = 0.f, b3v = 0.f;
        for (int j = jb; j < je; j += 8) {
            int i0 = j + ent4, i1 = j + 4 + ent4;
            bool v0 = i0 < je, v1 = i1 < je;
            int c0 = scol[v0 ? i0 : jb];
            int c1 = scol[v1 ? i1 : jb];
            ushort4v p0 = *(const ushort4v*)&xb[c0 * D + 4 * fl];
            ushort4v p1 = *(const ushort4v*)&xb[c1 * D + 4 * fl];
            if (v0) { a0 += bf2f(p0.x); a1 += bf2f(p0.y);
                      a2 += bf2f(p0.z); a3 += bf2f(p0.w); }
            if (v1) { b0v += bf2f(p1.x); b1v += bf2f(p1.y);
                      b2v += bf2f(p1.z); b3v += bf2f(p1.w); }
        }
        float s0 = a0 + b0v, s1 = a1 + b1v, s2 = a2 + b2v, s3 = a3 + b3v;
        s0 += __shfl_xor(s0, 16); s1 += __shfl_xor(s1, 16);
        s2 += __shfl_xor(s2, 16); s3 += __shfl_xor(s3, 16);
        s0 += __shfl_xor(s0, 32); s1 += __shfl_xor(s1, 32);
        s2 += __shfl_xor(s2, 32); s3 += __shfl_xor(s3, 32);
        if (lane < 16) {
            float4 xv = {0.f, 0.f, 0.f, 0.f};
            if (node < N_NODES) xv = *(const float4*)&x[(size_t)node * D + 4 * fl];
            ushort4v o;
            o.x = f2bf(fmaf(ep, xv.x, s0));
            o.y = f2bf(fmaf(ep, xv.y, s1));
            o.z = f2bf(fmaf(ep, xv.z, s2));
            o.w = f2bf(fmaf(ep, xv.w, s3));
            *(ushort4v*)&HB[nl][4 * fl] = o;
        }
    }
    __syncthreads();   // HB written by all waves, read by wave 0

    // ---- MLP: wave 0 owns the 16 nodes; weights from global (L1-hot) ----
    if (wid == 0) {
        int m = lane & 15, q = lane >> 4;
        short8 a0 = *(const short8*)&HB[m][q * 8];
        short8 a1 = *(const short8*)&HB[m][32 + q * 8];

        #pragma unroll
        for (int nt = 0; nt < 8; ++nt) {
            float bias = b1[nt * 16 + m];
            floatx4 acc = {bias, bias, bias, bias};
            short8 w0 = *(const short8*)&w1t[(nt * 16 + m) * D + q * 8];
            short8 w1 = *(const short8*)&w1t[(nt * 16 + m) * D + 32 + q * 8];
            acc = __builtin_amdgcn_mfma_f32_16x16x32_bf16(a0, w0, acc, 0, 0, 0);
            acc = __builtin_amdgcn_mfma_f32_16x16x32_bf16(a1, w1, acc, 0, 0, 0);
            #pragma unroll
            for (int r = 0; r < 4; ++r) {
                float hv = fmaxf(acc[r], 0.0f);
                HID[q * 4 + r][nt * 16 + m] = f2bf(hv);
            }
        }
        // wave-internal LDS RAW: compiler inserts lgkmcnt waits; no barrier

        short8 ha[4];
        #pragma unroll
        for (int kc2 = 0; kc2 < 4; ++kc2)
            ha[kc2] = *(const short8*)&HID[m][kc2 * 32 + q * 8];

        #pragma unroll
        for (int nt2 = 0; nt2 < 4; ++nt2) {
            float bias = b2[nt2 * 16 + m];
            floatx4 acc = {bias, bias, bias, bias};
            #pragma unroll
            for (int kc2 = 0; kc2 < 4; ++kc2) {
                short8 w = *(const short8*)&w2t[(nt2 * 16 + m) * H + kc2 * 32 + q * 8];
                acc = __builtin_amdgcn_mfma_f32_16x16x32_bf16(ha[kc2], w, acc, 0, 0, 0);
            }
            #pragma unroll
            for (int r = 0; r < 4; ++r) {
                int nn2 = bucket * 512 + sub * 16 + q * 4 + r;
                if (nn2 < N_NODES) out[(size_t)nn2 * D + nt2 * 16 + m] = acc[r];
            }
        }
    }
}

// ---------------------------------------------------------------------------
extern "C" void kernel_launch(void* const* d_in, const int* in_sizes, int n_in,
                              void* d_out, int out_size, void* d_ws, size_t ws_size,
                              hipStream_t stream) {
    const float* x   = (const float*)d_in[0];
    const int*   ei  = (const int*)  d_in[1];   // [2, 800000] int32
    const float* W1  = (const float*)d_in[2];
    const float* b1  = (const float*)d_in[3];
    const float* W2  = (const float*)d_in[4];
    const float* b2  = (const float*)d_in[5];
    const float* eps = (const float*)d_in[6];
    float* out = (float*)d_out;

    // ws (~20.9 MB): xb | w1t | w2t | csr(segments) | counts | csr2 | cursor2
    unsigned short* xb  = (unsigned short*)d_ws;          // 3.2M bf16, 6.4 MB
    unsigned short* w1t = xb + (size_t)N_NODES * D;       // 8192
    unsigned short* w2t = w1t + D * H;                    // 8192
    int* csr     = (int*)(w2t + D * H);                   // 391*98*64, 9.8 MB
    int* counts  = csr + (size_t)NBB * NLIVE * CAPT;      // 391*98, 153 KB
    int* csr2    = counts + (size_t)NBB * NLIVE;          // 3136*352, 4.42 MB
    int* cursor2 = csr2 + (size_t)NLIVE * 32 * SCAP2;     // 3136

    const int* row = ei;
    const int* col = ei + N_EDGES;

    bin_prep<<<NBB + 1, 512, 0, stream>>>(row, col, counts, csr, cursor2);
    subsort_conv<<<NSUBB + CVB, 256, 0, stream>>>(counts, csr, cursor2, csr2,
                                                  x, xb, W1, w1t, W2, w2t);
    gather_mlp<<<NLIVE * 32, 256, 0, stream>>>(x, xb, cursor2, csr2,
                                               w1t, b1, w2t, b2, eps, out);
}